// Round 19
// baseline (68.945 us; speedup 1.0000x reference)
//
#include <hip/hip_runtime.h>
#include <stdint.h>

// DeformConv1d: x[8,256,4096] f32, offsets[8,1,4094,3] f32,
// weight[256,256,3] f32, bias[256] f32 -> out[8,256,4094] f32.
//
// R18: ABLATION ROUND on R15 (best, 44.1us). Two kernels from one body:
//   deform_gemm_nostage: x-window staging/issue/drain REMOVED (Xt garbage,
//     barriers/Bp/A/MFMA/epilogue identical). Runs FIRST, writes garbage out.
//   deform_gemm_full: R15 verbatim. Runs LAST -> overwrites every output
//     element, so validation sees correct results.
// Decomposition: dur_us = pack(~3) + V_nostage + V_full(~41, calibrated by
// rocprof rows). Pre-committed read: V_nostage <= 33us -> staging exposure
// is the lever (restructure staging next); >= 38us -> staging already
// hidden, ablate MFMA/A next.

constexpr int CIN  = 256;
constexpr int LX   = 4096;
constexpr int KT   = 3;
constexpr int OUTL = 4094;
constexpr int COUT = 256;
constexpr int NQ   = 24;    // K-chunks of 32
constexpr int EPIW = 68;    // padded epilogue row (floats)
constexpr int NIT  = 2176;  // 128 c * 17 float4-groups per half

typedef __attribute__((ext_vector_type(8))) short bf16x8;
typedef __attribute__((ext_vector_type(4))) float f32x4;
typedef __attribute__((ext_vector_type(16))) float f32x16;

__device__ __forceinline__ short f2bf(float f) {        // round-half-up
  union { float f; uint32_t u; } v; v.f = f;
  return (short)((v.u + 0x8000u) >> 16);
}
__device__ __forceinline__ float bf2f(short s) {
  union { uint32_t u; float f; } v;
  v.u = ((uint32_t)(uint16_t)s) << 16;
  return v.f;
}
__device__ __forceinline__ float4 loadx4(const float* p, int l) {
  if (l + 3 < LX) return *(const float4*)(p + l);   // l is 16B-aligned
  float4 v; v.x = v.y = v.z = v.w = 0.f;
  if (l + 0 < LX) v.x = p[l + 0];
  if (l + 1 < LX) v.y = p[l + 1];
  if (l + 2 < LX) v.z = p[l + 2];
  return v;
}

// A pack: shorts idx = ((q*2+h)*8 + mf)*512 + l*8 + j   (same as R14/R15)
__global__ __launch_bounds__(256) void pack_weights_kernel(
    const float* __restrict__ w, short* __restrict__ ap) {
  const int gid = blockIdx.x * 256 + threadIdx.x;
  if (gid >= NQ * 2 * 8 * 64) return;
  const int l   = gid & 63;
  const int mf  = (gid >> 6) & 7;
  const int h   = (gid >> 9) & 1;
  const int q   = gid >> 10;
  const int ch  = q / 12;
  const int ks  = q % 12;
  const int tap = ks >> 2;
  const int c0  = ch * 128 + (ks & 3) * 32 + h * 16 + (l >> 5) * 8;
  const int row = mf * 32 + (l & 31);
  bf16x8 v;
  #pragma unroll
  for (int j = 0; j < 8; ++j) {
    v[j] = f2bf(w[((size_t)row * CIN + c0 + j) * KT + tap]);
  }
  *(bf16x8*)(ap + (size_t)gid * 8) = v;
}

template<bool NOSTAGE>
__device__ __forceinline__ void gemm_body(
    const float* __restrict__ x, const float* __restrict__ off,
    const short* __restrict__ ap, const float* __restrict__ bias,
    float* __restrict__ out) {

  __shared__ __align__(16) char smem[2 * 17408 + 16384 + 1024];
  short* Xt0   = (short*)smem;
  short* Xt1   = (short*)(smem + 17408);
  short* Bp    = (short*)(smem + 34816);
  float* Epi   = (float*)smem;
  float* biasS = (float*)(smem + 51200);

  const int tid  = threadIdx.x;
  const int lane = tid & 63;
  const int wid  = tid >> 6;
  const int l31  = lane & 31;
  const int lh   = lane >> 5;

  const int b    = blockIdx.x & 7;
  const int rest = blockIdx.x >> 3;
  const int th   = rest & 1;
  const int tt   = rest >> 1;
  const int t0   = tt * 128 + th * 64;

  float w0m[3], w1m[3];
  int   d0m[3];
  {
    const int t = t0 + (tid & 63);
    #pragma unroll
    for (int k = 0; k < KT; ++k) {
      float w0 = 0.f, w1 = 0.f; int d0 = 0;
      if (t < OUTL) {
        const float o = off[((size_t)b * OUTL + t) * KT + k];
        float T = (float)(t + k) + o;
        T = fminf(fmaxf(T, (float)t), (float)(t + 2));
        int U0 = (int)T;
        if (U0 > LX - 2) U0 = LX - 2;
        w1 = T - (float)U0;
        w0 = 1.f - w1;
        d0 = U0 - t0;
      }
      w0m[k] = w0; w1m[k] = w1; d0m[k] = d0;
    }
  }
  if (tid < COUT) biasS[tid] = bias[tid];

  f32x16 acc0 = {0.f,0.f,0.f,0.f,0.f,0.f,0.f,0.f,0.f,0.f,0.f,0.f,0.f,0.f,0.f,0.f};
  f32x16 acc1 = {0.f,0.f,0.f,0.f,0.f,0.f,0.f,0.f,0.f,0.f,0.f,0.f,0.f,0.f,0.f,0.f};

  const float* xb = x + (size_t)b * CIN * LX;

  const short* apw = ap + wid * 512 + lane * 8;
  bf16x8 aC0 = *(const bf16x8*)apw;
  bf16x8 aC1 = *(const bf16x8*)(apw + 4096);

  float4 xv[5];

  // ---- prologue: stage ch0 window (ablatable) ----
  if constexpr (!NOSTAGE) {
    #pragma unroll
    for (int r = 0; r < 5; ++r) {
      const int idx = r * 512 + tid;
      if (idx < NIT) {
        const int c = idx / 17, g = idx - c * 17;
        xv[r] = loadx4(xb + (size_t)c * LX, t0 + 4 * g);
      }
    }
    #pragma unroll
    for (int r = 0; r < 5; ++r) {
      const int idx = r * 512 + tid;
      if (idx < NIT) {
        const int c = idx / 17, g = idx - c * 17;
        const float fe[4] = {xv[r].x, xv[r].y, xv[r].z, xv[r].w};
        #pragma unroll
        for (int e = 0; e < 4; ++e) {
          const int pos = g * 4 + e;
          Xt0[(pos * 128 + c) ^ ((pos & 7) << 3)] = f2bf(fe[e]);
        }
      }
    }
  }
  __syncthreads();

  // ---- issue ch1 window loads (ablatable) ----
  if constexpr (!NOSTAGE) {
    #pragma unroll
    for (int r = 0; r < 5; ++r) {
      const int idx = r * 512 + tid;
      if (idx < NIT) {
        const int c = idx / 17, g = idx - c * 17;
        xv[r] = loadx4(xb + (size_t)(128 + c) * LX, t0 + 4 * g);
      }
    }
  }

  #pragma unroll 1
  for (int ch = 0; ch < 2; ++ch) {
    short* Xc = ch ? Xt1 : Xt0;

    #pragma unroll
    for (int tap = 0; tap < KT; ++tap) {
      if (tap | ch) __syncthreads();

      // ---- build Bp[t][c] (swizzled) ----
      {
        const int tq = tid & 63;
        const int c0 = (tid >> 6) * 16;
        const float w0 = w0m[tap], w1 = w1m[tap];
        const int   d0 = d0m[tap];
        const int sw0 = (d0 & 7) << 3;
        const int sw1 = ((d0 + 1) & 7) << 3;
        const int r0i = d0 * 128, r1i = (d0 + 1) * 128;
        const bf16x8 r0a = *(const bf16x8*)&Xc[(r0i + c0)     ^ sw0];
        const bf16x8 r0b = *(const bf16x8*)&Xc[(r0i + c0 + 8) ^ sw0];
        const bf16x8 r1a = *(const bf16x8*)&Xc[(r1i + c0)     ^ sw1];
        const bf16x8 r1b = *(const bf16x8*)&Xc[(r1i + c0 + 8) ^ sw1];
        bf16x8 o1, o2;
        #pragma unroll
        for (int j = 0; j < 8; ++j) {
          o1[j] = f2bf(bf2f(r0a[j]) * w0 + bf2f(r1a[j]) * w1);
          o2[j] = f2bf(bf2f(r0b[j]) * w0 + bf2f(r1b[j]) * w1);
        }
        const int swt = (tq & 7) << 3;
        *(bf16x8*)&Bp[(tq * 128 + c0)     ^ swt] = o1;
        *(bf16x8*)&Bp[(tq * 128 + c0 + 8) ^ swt] = o2;
      }
      __syncthreads();

      // ---- 4 barrier-free K-steps ----
      #pragma unroll 1
      for (int csub = 0; csub < 4; ++csub) {
        const int q  = ch * 12 + tap * 4 + csub;
        const int qn = q < NQ - 1 ? q + 1 : NQ - 1;
        const bf16x8 aN0 = *(const bf16x8*)(apw + (size_t)qn * 8192);
        const bf16x8 aN1 = *(const bf16x8*)(apw + (size_t)qn * 8192 + 4096);

        const int cbase = csub * 32 + lh * 8;
        const int ta = l31,      swa = (ta & 7) << 3;
        const int tb = 32 + l31, swb = (tb & 7) << 3;
        const bf16x8 b00 = *(const bf16x8*)&Bp[(ta * 128 + cbase)      ^ swa];
        const bf16x8 b01 = *(const bf16x8*)&Bp[(ta * 128 + cbase + 16) ^ swa];
        const bf16x8 b10 = *(const bf16x8*)&Bp[(tb * 128 + cbase)      ^ swb];
        const bf16x8 b11 = *(const bf16x8*)&Bp[(tb * 128 + cbase + 16) ^ swb];

        acc0 = __builtin_amdgcn_mfma_f32_32x32x16_bf16(aC0, b00, acc0, 0, 0, 0);
        acc0 = __builtin_amdgcn_mfma_f32_32x32x16_bf16(aC1, b01, acc0, 0, 0, 0);
        acc1 = __builtin_amdgcn_mfma_f32_32x32x16_bf16(aC0, b10, acc1, 0, 0, 0);
        acc1 = __builtin_amdgcn_mfma_f32_32x32x16_bf16(aC1, b11, acc1, 0, 0, 0);

        aC0 = aN0; aC1 = aN1;
      }
    }

    // ---- ch boundary: drain ch1 loads (ablatable) ----
    if constexpr (!NOSTAGE) {
      if (ch == 0) {
        #pragma unroll
        for (int r = 0; r < 5; ++r) {
          const int idx = r * 512 + tid;
          if (idx < NIT) {
            const int c = idx / 17, g = idx - c * 17;
            const float fe[4] = {xv[r].x, xv[r].y, xv[r].z, xv[r].w};
            #pragma unroll
            for (int e = 0; e < 4; ++e) {
              const int pos = g * 4 + e;
              Xt1[(pos * 128 + c) ^ ((pos & 7) << 3)] = f2bf(fe[e]);
            }
          }
        }
      }
    }
  }

  // ---- epilogue (identical in both variants; writes out) ----
  const size_t obase = (size_t)b * COUT * OUTL;
  #pragma unroll
  for (int p = 0; p < 4; ++p) {
    __syncthreads();
    if ((wid >> 1) == p) {
      const int lrb = (wid & 1) * 32;
      #pragma unroll
      for (int r = 0; r < 16; ++r) {
        const int rowl = (r & 3) + 8 * (r >> 2) + 4 * lh;
        const int grow = p * 64 + lrb + rowl;
        Epi[(lrb + rowl) * EPIW + l31]      = acc0[r] + biasS[grow];
        Epi[(lrb + rowl) * EPIW + 32 + l31] = acc1[r] + biasS[grow];
      }
    }
    __syncthreads();
    const int rr = tid >> 3;
    const int c8 = (tid & 7) * 8;
    float* op = out + obase + (size_t)(p * 64 + rr) * OUTL + t0 + c8;
    const f32x4 v0 = *(const f32x4*)&Epi[rr * EPIW + c8];
    const f32x4 v1 = *(const f32x4*)&Epi[rr * EPIW + c8 + 4];
    if (t0 + c8 + 7 < OUTL) {
      *(f32x4*)op = v0;
      *(f32x4*)(op + 4) = v1;
    } else {
      #pragma unroll
      for (int e = 0; e < 4; ++e) {
        if (t0 + c8 + e < OUTL)     op[e]     = v0[e];
        if (t0 + c8 + 4 + e < OUTL) op[4 + e] = v1[e];
      }
    }
  }
}

__global__ __launch_bounds__(512, 4) void deform_gemm_nostage(
    const float* __restrict__ x, const float* __restrict__ off,
    const short* __restrict__ ap, const float* __restrict__ bias,
    float* __restrict__ out) {
  gemm_body<true>(x, off, ap, bias, out);
}

__global__ __launch_bounds__(512, 4) void deform_gemm_full(
    const float* __restrict__ x, const float* __restrict__ off,
    const short* __restrict__ ap, const float* __restrict__ bias,
    float* __restrict__ out) {
  gemm_body<false>(x, off, ap, bias, out);
}

extern "C" void kernel_launch(void* const* d_in, const int* in_sizes, int n_in,
                              void* d_out, int out_size, void* d_ws, size_t ws_size,
                              hipStream_t stream) {
  const float* x    = (const float*)d_in[0];
  const float* off  = (const float*)d_in[1];
  const float* wgt  = (const float*)d_in[2];
  const float* bias = (const float*)d_in[3];
  float* out  = (float*)d_out;
  short* ap   = (short*)d_ws;   // 393216 B of scratch

  pack_weights_kernel<<<dim3(NQ * 2 * 8 * 64 / 256), dim3(256), 0, stream>>>(wgt, ap);
  // ablated variant first (writes garbage out), full variant LAST
  // (full coverage overwrite -> validation sees correct output).
  deform_gemm_nostage<<<dim3(512), dim3(512), 0, stream>>>(x, off, ap, bias, out);
  deform_gemm_full<<<dim3(512), dim3(512), 0, stream>>>(x, off, ap, bias, out);
}

// Round 20
// 40.390 us; speedup vs baseline: 1.7070x; 1.7070x over previous
//
#include <hip/hip_runtime.h>
#include <stdint.h>

// DeformConv1d: x[8,256,4096] f32, offsets[8,1,4094,3] f32,
// weight[256,256,3] f32, bias[256] f32 -> out[8,256,4094] f32.
//
// R20: staging made near-free (R18 ablation: staging = ~32us of 49,
// GEMM core only ~17us).
//  - Xs[c][pos] f32 NON-transposed window: staging = float4 load ->
//    ds_write_b128 (16B-aligned). Zero f2bf VALU, zero scalar writes,
//    no registers held across GEMM -> no spills.
//  - Transpose tax moves into the Bp build (runs once per (ch,tap)):
//    32 scalar ds_read_b32 f32 gathers per thread; interp reads f32
//    directly (no bf2f). Banks: stride 68 % 32 == 4 -> spread; lanes
//    differ in d0 -> ~2-way (free).
//  - Single-buffered Xs (52.2KB LDS), serial stage between halves
//    (~2x800cy, covered by the 2nd resident block). No async holding.
// Unchanged from R18-full: 32x32x16 MFMA, wave-private A from L2 +
// prefetch, swizzled Bp, register meta, LDS epilogue, XCD decode,
// grid 512 x 512 threads.

constexpr int CIN  = 256;
constexpr int LX   = 4096;
constexpr int KT   = 3;
constexpr int OUTL = 4094;
constexpr int COUT = 256;
constexpr int WPOS = 68;    // window positions staged (t0 .. t0+67)
constexpr int NQ   = 24;    // K-chunks of 32
constexpr int EPIW = 68;    // padded epilogue row (floats)
constexpr int NIT  = 2176;  // 128 c * 17 float4-groups per half

typedef __attribute__((ext_vector_type(8))) short bf16x8;
typedef __attribute__((ext_vector_type(4))) float f32x4;
typedef __attribute__((ext_vector_type(16))) float f32x16;

__device__ __forceinline__ short f2bf(float f) {        // round-half-up
  union { float f; uint32_t u; } v; v.f = f;
  return (short)((v.u + 0x8000u) >> 16);
}
__device__ __forceinline__ float4 loadx4(const float* p, int l) {
  if (l + 3 < LX) return *(const float4*)(p + l);   // l is 16B-aligned
  float4 v; v.x = v.y = v.z = v.w = 0.f;
  if (l + 0 < LX) v.x = p[l + 0];
  if (l + 1 < LX) v.y = p[l + 1];
  if (l + 2 < LX) v.z = p[l + 2];
  return v;
}

// A pack: shorts idx = ((q*2+h)*8 + mf)*512 + l*8 + j   (same as R14/R15)
__global__ __launch_bounds__(256) void pack_weights_kernel(
    const float* __restrict__ w, short* __restrict__ ap) {
  const int gid = blockIdx.x * 256 + threadIdx.x;
  if (gid >= NQ * 2 * 8 * 64) return;
  const int l   = gid & 63;
  const int mf  = (gid >> 6) & 7;
  const int h   = (gid >> 9) & 1;
  const int q   = gid >> 10;
  const int ch  = q / 12;
  const int ks  = q % 12;
  const int tap = ks >> 2;
  const int c0  = ch * 128 + (ks & 3) * 32 + h * 16 + (l >> 5) * 8;
  const int row = mf * 32 + (l & 31);
  bf16x8 v;
  #pragma unroll
  for (int j = 0; j < 8; ++j) {
    v[j] = f2bf(w[((size_t)row * CIN + c0 + j) * KT + tap]);
  }
  *(bf16x8*)(ap + (size_t)gid * 8) = v;
}

__global__ __launch_bounds__(512, 4) void deform_gemm_kernel(
    const float* __restrict__ x, const float* __restrict__ off,
    const short* __restrict__ ap, const float* __restrict__ bias,
    float* __restrict__ out) {

  // arena: [0,34816) Xs f32 [128][68] / Epi (64x68 f32 = 17408B, reuse),
  //        [34816,51200) Bp (64x128 bf16), [51200,52224) biasS
  __shared__ __align__(16) char smem[34816 + 16384 + 1024];
  float* Xs    = (float*)smem;
  short* Bp    = (short*)(smem + 34816);
  float* Epi   = (float*)smem;
  float* biasS = (float*)(smem + 51200);

  const int tid  = threadIdx.x;
  const int lane = tid & 63;
  const int wid  = tid >> 6;       // 0..7 = M-frag index
  const int l31  = lane & 31;
  const int lh   = lane >> 5;      // k-half within fragment

  // decode: b in low 3 bits (XCD-chunk); th pairs at bid stride 8
  const int b    = blockIdx.x & 7;        // 8 batches
  const int rest = blockIdx.x >> 3;       // 0..63
  const int th   = rest & 1;              // t-half
  const int tt   = rest >> 1;             // 32 coarse t-tiles
  const int t0   = tt * 128 + th * 64;

  // ---- per-thread interp meta for the Bp build (t = t0 + (tid&63)) ----
  float w0m[3], w1m[3];
  int   d0m[3];
  {
    const int t = t0 + (tid & 63);
    #pragma unroll
    for (int k = 0; k < KT; ++k) {
      float w0 = 0.f, w1 = 0.f; int d0 = 0;
      if (t < OUTL) {
        const float o = off[((size_t)b * OUTL + t) * KT + k];
        float T = (float)(t + k) + o;
        T = fminf(fmaxf(T, (float)t), (float)(t + 2));  // clip to [t, t+2]
        int U0 = (int)T;                                 // floor (T >= 0)
        if (U0 > LX - 2) U0 = LX - 2;
        w1 = T - (float)U0;                              // in [0,1]
        w0 = 1.f - w1;
        d0 = U0 - t0;                                    // in [0, 66]
      }
      w0m[k] = w0; w1m[k] = w1; d0m[k] = d0;
    }
  }
  if (tid < COUT) biasS[tid] = bias[tid];

  f32x16 acc0 = {0.f,0.f,0.f,0.f,0.f,0.f,0.f,0.f,0.f,0.f,0.f,0.f,0.f,0.f,0.f,0.f};
  f32x16 acc1 = {0.f,0.f,0.f,0.f,0.f,0.f,0.f,0.f,0.f,0.f,0.f,0.f,0.f,0.f,0.f,0.f};

  const float* xb = x + (size_t)b * CIN * LX;

  // A: wave-private coalesced loads; preload step 0 (both K16 halves)
  const short* apw = ap + wid * 512 + lane * 8;
  bf16x8 aC0 = *(const bf16x8*)apw;
  bf16x8 aC1 = *(const bf16x8*)(apw + 4096);

  #pragma unroll 1
  for (int ch = 0; ch < 2; ++ch) {            // c-halves (ROLLED)
    if (ch) __syncthreads();                  // prev half's Xs readers done
    // ---- stage x window half: f32, NON-transposed, b128 writes ----
    // idx -> (c = idx/17, g = idx%17); write Xs[c][4g..4g+3].
    // offset (c*68+4g)*4 = c*272 + g*16: 16B-aligned. Zero VALU convert.
    #pragma unroll
    for (int r = 0; r < 5; ++r) {
      const int idx = r * 512 + tid;
      if (idx < NIT) {
        const int c = idx / 17, g = idx - c * 17;
        const float4 v = loadx4(xb + (size_t)(ch * 128 + c) * LX, t0 + 4 * g);
        *(float4*)&Xs[c * WPOS + 4 * g] = v;
      }
    }
    __syncthreads();  // window (and bias on first pass) visible

    #pragma unroll
    for (int tap = 0; tap < KT; ++tap) {      // UNROLLED: static meta index
      if (tap) __syncthreads();               // drain prev tap's Bp readers

      // ---- build Bp[t][c] (swizzled): f32 gather from Xs ----
      // thread: t = tid&63, c-range = (tid>>6)*16 .. +15
      {
        const int tq = tid & 63;
        const int cb = (tid >> 6) * 16;
        const float w0 = w0m[tap], w1 = w1m[tap];
        const int   d0 = d0m[tap];
        const int swt = (tq & 7) << 3;
        bf16x8 o1, o2;
        #pragma unroll
        for (int j = 0; j < 8; ++j) {
          const float xa0 = Xs[(cb + j) * WPOS + d0];
          const float xa1 = Xs[(cb + j) * WPOS + d0 + 1];
          o1[j] = f2bf(xa0 * w0 + xa1 * w1);
        }
        *(bf16x8*)&Bp[(tq * 128 + cb) ^ swt] = o1;
        #pragma unroll
        for (int j = 0; j < 8; ++j) {
          const float xb0 = Xs[(cb + 8 + j) * WPOS + d0];
          const float xb1 = Xs[(cb + 8 + j) * WPOS + d0 + 1];
          o2[j] = f2bf(xb0 * w0 + xb1 * w1);
        }
        *(bf16x8*)&Bp[(tq * 128 + cb + 8) ^ swt] = o2;
      }
      __syncthreads();  // Bp ready

      // ---- 4 barrier-free K-steps (K=32 each) ----
      #pragma unroll 1
      for (int csub = 0; csub < 4; ++csub) {
        const int q  = ch * 12 + tap * 4 + csub;
        const int qn = q < NQ - 1 ? q + 1 : NQ - 1;
        // prefetch next step's A (wave-private, L2-hot)
        const bf16x8 aN0 = *(const bf16x8*)(apw + (size_t)qn * 8192);
        const bf16x8 aN1 = *(const bf16x8*)(apw + (size_t)qn * 8192 + 4096);

        // B-frags: lane = col t' = jn*32+l31; elem j -> c = cbase + j (+16)
        const int cbase = csub * 32 + lh * 8;
        const int ta = l31,      swa = (ta & 7) << 3;  // jn = 0
        const int tb = 32 + l31, swb = (tb & 7) << 3;  // jn = 1
        {
          const bf16x8 b00 = *(const bf16x8*)&Bp[(ta * 128 + cbase) ^ swa];
          const bf16x8 b10 = *(const bf16x8*)&Bp[(tb * 128 + cbase) ^ swb];
          acc0 = __builtin_amdgcn_mfma_f32_32x32x16_bf16(aC0, b00, acc0, 0, 0, 0);
          acc1 = __builtin_amdgcn_mfma_f32_32x32x16_bf16(aC0, b10, acc1, 0, 0, 0);
        }
        {
          const bf16x8 b01 = *(const bf16x8*)&Bp[(ta * 128 + cbase + 16) ^ swa];
          const bf16x8 b11 = *(const bf16x8*)&Bp[(tb * 128 + cbase + 16) ^ swb];
          acc0 = __builtin_amdgcn_mfma_f32_32x32x16_bf16(aC1, b01, acc0, 0, 0, 0);
          acc1 = __builtin_amdgcn_mfma_f32_32x32x16_bf16(aC1, b11, acc1, 0, 0, 0);
        }
        aC0 = aN0; aC1 = aN1;
      }
    }
  }

  // ---- epilogue: LDS-staged, contiguous row-segment stores ----
  // 4 passes of 64 rows; producers = waves 2p, 2p+1 (their own M-frags).
  // 32x32 C/D layout: col = lane&31, row = (r&3) + 8*(r>>2) + 4*(lane>>5).
  const size_t obase = (size_t)b * COUT * OUTL;
  #pragma unroll
  for (int p = 0; p < 4; ++p) {
    __syncthreads();   // p==0: Xs->Epi reuse safe; else: prev consume done
    if ((wid >> 1) == p) {
      const int lrb = (wid & 1) * 32;
      #pragma unroll
      for (int r = 0; r < 16; ++r) {
        const int rowl = (r & 3) + 8 * (r >> 2) + 4 * lh;   // 0..31
        const int grow = p * 64 + lrb + rowl;               // == wid*32+rowl
        Epi[(lrb + rowl) * EPIW + l31]      = acc0[r] + biasS[grow];
        Epi[(lrb + rowl) * EPIW + 32 + l31] = acc1[r] + biasS[grow];
      }
    }
    __syncthreads();
    // consumer: 512 threads, 64 x 64 f32 tile; 32B per thread
    const int rr = tid >> 3;               // 0..63
    const int c8 = (tid & 7) * 8;          // 0..56
    float* op = out + obase + (size_t)(p * 64 + rr) * OUTL + t0 + c8;
    const f32x4 v0 = *(const f32x4*)&Epi[rr * EPIW + c8];
    const f32x4 v1 = *(const f32x4*)&Epi[rr * EPIW + c8 + 4];
    if (t0 + c8 + 7 < OUTL) {
      *(f32x4*)op = v0;
      *(f32x4*)(op + 4) = v1;
    } else {
      #pragma unroll
      for (int e = 0; e < 4; ++e) {
        if (t0 + c8 + e < OUTL)     op[e]     = v0[e];
        if (t0 + c8 + 4 + e < OUTL) op[4 + e] = v1[e];
      }
    }
  }
}

extern "C" void kernel_launch(void* const* d_in, const int* in_sizes, int n_in,
                              void* d_out, int out_size, void* d_ws, size_t ws_size,
                              hipStream_t stream) {
  const float* x    = (const float*)d_in[0];
  const float* off  = (const float*)d_in[1];
  const float* wgt  = (const float*)d_in[2];
  const float* bias = (const float*)d_in[3];
  float* out  = (float*)d_out;
  short* ap   = (short*)d_ws;   // 393216 B of scratch

  // pack weights into wave-private coalesced A layout (~3 us)
  pack_weights_kernel<<<dim3(NQ * 2 * 8 * 64 / 256), dim3(256), 0, stream>>>(wgt, ap);
  // 8 b x 32 tt x 2 th = 512 blocks (2/CU), 512 threads (8 waves)
  deform_gemm_kernel<<<dim3(512), dim3(512), 0, stream>>>(x, off, ap, bias, out);
}